// Round 1
// baseline (39.826 us; speedup 1.0000x reference)
//
#include <hip/hip_runtime.h>

typedef __attribute__((ext_vector_type(8))) short bf16x8;
typedef __attribute__((ext_vector_type(4))) float f32x4;

constexpr int FEAT = 64;            // in features (= out features)
constexpr int PIX_PER_BLK = 128;    // pixels per block (4 waves x 32)
constexpr int CHUNK_F = 4;          // f-slices per staged W chunk
constexpr int CHUNK_USHORT = CHUNK_F * FEAT * 64;   // 16384 bf16 = 32 KB
constexpr int NCHUNK = FEAT / CHUNK_F;              // 16

__device__ __forceinline__ unsigned short bf_rne(float f) {
  unsigned u = __float_as_uint(f);
  return (unsigned short)((u + 0x7fffu + ((u >> 16) & 1u)) >> 16);
}

// ---- prepass: W fp32 -> bf16 (RNE) into workspace ----
__global__ __launch_bounds__(256) void wcvt_kernel(const float* __restrict__ W,
                                                   unsigned short* __restrict__ Wb) {
  int i = (blockIdx.x * 256 + threadIdx.x) * 4;   // 256 blocks x 256 thr x 4 = 262144 exact
  float4 w = *reinterpret_cast<const float4*>(W + i);
  ushort4 r;
  r.x = bf_rne(w.x);
  r.y = bf_rne(w.y);
  r.z = bf_rne(w.z);
  r.w = bf_rne(w.w);
  *reinterpret_cast<ushort4*>(Wb + i) = r;
}

// ---- main fused bilinear kernel ----
__global__ __launch_bounds__(256, 1) void quad_kernel(const float* __restrict__ x,
                                                      const unsigned short* __restrict__ Wb,
                                                      float* __restrict__ out) {
  __shared__ float xT[64][129];                       // x tile transposed, fp32 (33 KB), +1 pad
  __shared__ alignas(16) unsigned short Ws[2][CHUNK_USHORT];  // W chunk double buffer (64 KB)

  const int t = threadIdx.x;
  const int lane = t & 63;
  const int wv = t >> 6;        // wave 0..3
  const int q = lane >> 4;      // k-quarter 0..3
  const int r16 = lane & 15;
  const long pb = (long)blockIdx.x * PIX_PER_BLK;

  // stage one 4-f W chunk into Ws[buf] via global_load_lds (linear LDS dest,
  // inverse-swizzled global source; read side applies the same XOR -> both-sides swizzle)
  auto stage = [&](int chunk, int buf) {
    const char* wbase = reinterpret_cast<const char*>(Wb) + chunk * (CHUNK_F * FEAT * 2); // +512 B per chunk along each row
    char* ldsbase = reinterpret_cast<char*>(&Ws[buf][0]);
#pragma unroll
    for (int rr = 0; rr < 8; ++rr) {
      int linear = (rr * 256 + t) * 16;        // byte offset within chunk buffer
      int o = linear >> 9;                     // 512 B per o-row
      int rb = linear & 511;
      int lrb = rb ^ ((o & 7) << 4);           // involution on bits 4..6
      const char* src = wbase + o * 8192 + lrb;       // Wb row stride = 4096*2 B
      char* dst = ldsbase + (rr * 256 + wv * 64) * 16; // wave-uniform base (+lane*16 by HW)
      __builtin_amdgcn_global_load_lds(
          (const __attribute__((address_space(1))) void*)src,
          (__attribute__((address_space(3))) void*)dst, 16, 0, 0);
    }
  };

  stage(0, 0);   // start chunk-0 fetch early

  // x tile -> LDS transposed (fp32): 128 rows x 64 f
  {
    const float4* xg = reinterpret_cast<const float4*>(x + pb * FEAT);
#pragma unroll
    for (int c = 0; c < 8; ++c) {
      int e4 = c * 256 + t;
      float4 v = xg[e4];
      int p = (e4 * 4) >> 6;
      int f0 = (e4 * 4) & 63;
      xT[f0 + 0][p] = v.x;
      xT[f0 + 1][p] = v.y;
      xT[f0 + 2][p] = v.z;
      xT[f0 + 3][p] = v.w;
    }
  }
  __syncthreads();   // xT ready for all waves

  // preload this lane's g-chunks (fp32), reused across the whole f loop
  float xr[2][2][8];
#pragma unroll
  for (int m = 0; m < 2; ++m)
#pragma unroll
    for (int ks = 0; ks < 2; ++ks)
#pragma unroll
      for (int b = 0; b < 8; ++b)
        xr[m][ks][b] = xT[ks * 32 + q * 8 + b][wv * 32 + m * 16 + r16];

  f32x4 acc[2][4] = {};   // [mrep][ntile], 32 fp32 accumulators

  for (int c = 0; c < NCHUNK; ++c) {
    // barrier drains vmcnt -> chunk c resident in Ws[c&1]; also guarantees all
    // waves finished reading Ws[(c+1)&1] (used in iter c-1) before we overwrite it
    __syncthreads();
    if (c + 1 < NCHUNK) stage(c + 1, (c + 1) & 1);
    const char* wsb = reinterpret_cast<const char*>(&Ws[c & 1][0]);

#pragma unroll
    for (int fl = 0; fl < CHUNK_F; ++fl) {
      int f = c * CHUNK_F + fl;
      float xf0 = xT[f][wv * 32 + r16];        // broadcast reads, conflict-free
      float xf1 = xT[f][wv * 32 + 16 + r16];

      // A fragments: x[p,f] * x[p,g] in fp32, truncate-pack to bf16 via v_perm
      bf16x8 afr[2][2];
#pragma unroll
      for (int m = 0; m < 2; ++m) {
        float xf = m ? xf1 : xf0;
#pragma unroll
        for (int ks = 0; ks < 2; ++ks) {
          union { unsigned u[4]; bf16x8 v; } pk;
#pragma unroll
          for (int i = 0; i < 4; ++i) {
            unsigned p0 = __float_as_uint(xf * xr[m][ks][2 * i]);
            unsigned p1 = __float_as_uint(xf * xr[m][ks][2 * i + 1]);
            pk.u[i] = __builtin_amdgcn_perm(p1, p0, 0x07060302u);  // {hi16(p1),hi16(p0)}
          }
          afr[m][ks] = pk.v;
        }
      }

      // B fragments from swizzled LDS + MFMA
#pragma unroll
      for (int nt = 0; nt < 4; ++nt) {
        int o = nt * 16 + r16;
        int swz = (o & 7) << 4;
#pragma unroll
        for (int ks = 0; ks < 2; ++ks) {
          int X = (fl * 64 + ks * 32 + q * 8) * 2;
          bf16x8 bfr = *reinterpret_cast<const bf16x8*>(wsb + o * 512 + (X ^ swz));
#pragma unroll
          for (int m = 0; m < 2; ++m)
            acc[m][nt] = __builtin_amdgcn_mfma_f32_16x16x32_bf16(afr[m][ks], bfr,
                                                                 acc[m][nt], 0, 0, 0);
        }
      }
    }
  }

  // epilogue: D row = q*4 + reg, col = r16 (verified C/D layout)
#pragma unroll
  for (int m = 0; m < 2; ++m)
#pragma unroll
    for (int nt = 0; nt < 4; ++nt)
#pragma unroll
      for (int b = 0; b < 4; ++b) {
        long prow = pb + wv * 32 + m * 16 + q * 4 + b;
        out[prow * 64 + nt * 16 + r16] = acc[m][nt][b];
      }
}

extern "C" void kernel_launch(void* const* d_in, const int* in_sizes, int n_in,
                              void* d_out, int out_size, void* d_ws, size_t ws_size,
                              hipStream_t stream) {
  const float* x = (const float*)d_in[0];
  const float* W = (const float*)d_in[1];
  float* out = (float*)d_out;
  unsigned short* Wb = (unsigned short*)d_ws;   // 512 KB bf16 W

  hipLaunchKernelGGL(wcvt_kernel, dim3(256), dim3(256), 0, stream, W, Wb);
  hipLaunchKernelGGL(quad_kernel, dim3(256), dim3(256), 0, stream, x, Wb, out);
}